// Round 1
// baseline (631.934 us; speedup 1.0000x reference)
//
#include <hip/hip_runtime.h>
#include <math.h>

#define Bq 16
#define Tq 34
#define Nq 1000
#define Cq 32      // CIN == DC == 32
#define OCq 64
#define Eq 16000
#define TPq 32     // T - dilation
#define Gq (Bq*TPq)  // 512 graphs
#define NG8 (Nq/8)   // 125

__device__ __forceinline__ float fast_tanh(float x) {
    float xc = fminf(fmaxf(x, -15.f), 15.f);
    float u  = __expf(2.f * xc);
    return 1.f - 2.f * __builtin_amdgcn_rcpf(u + 1.f);
}
__device__ __forceinline__ float fast_sigmoid(float x) {
    float xc = fminf(fmaxf(x, -30.f), 30.f);
    return __builtin_amdgcn_rcpf(1.f + __expf(-xc));
}
__device__ __forceinline__ unsigned bf16_bits(float f) {
    unsigned u = __float_as_uint(f);
    return (u + 0x7fffu + ((u >> 16) & 1u)) >> 16;   // RNE
}
__device__ __forceinline__ unsigned pack_bf16x2(float lo, float hi) {
    return bf16_bits(lo) | (bf16_bits(hi) << 16);
}

// ---------------------------------------------------------------------------
// K1: fused dilated gated conv -> out1 [B,32,N,32] (fp32)  and
//     xwt = gated @ Wgcn^T packed bf16, layout uint4[(n*2+s)*4 + c8][gl].
// Weights are wave-uniform -> read straight from global with uniform indices
// (scalar s_load path, K$-cached). LDS holds ONLY the x tile (35 KB ->
// 4 blocks/CU). This takes the 1280 broadcast ds_read_b128/thread of the
// previous version off the DS pipe, which was the ~200 us bottleneck.
// GCN matmul deferred: go[32] kept in regs, then c-outer loop reads wgcn
// rows contiguously (no transposed staging needed).
// ---------------------------------------------------------------------------
__global__ __launch_bounds__(256) void k_conv(
    const float* __restrict__ x,
    const float* __restrict__ wg1, const float* __restrict__ bg1,
    const float* __restrict__ wg2, const float* __restrict__ bg2,
    const float* __restrict__ wgcn,
    float* __restrict__ out1, uint4* __restrict__ xw4)
{
    __shared__ float xs[34*260];      // [t][n*32+c], stride 260 (16B-aligned pad)
    const int tid = threadIdx.x;
    const int b   = blockIdx.x / NG8;
    const int n0  = (blockIdx.x % NG8) * 8;

    const float* xsrc = x + ((size_t)b*Tq*Nq + n0)*Cq;
    #pragma unroll
    for (int j = 0; j < Tq; j++)
        xs[j*260 + tid] = xsrc[(size_t)j*Nq*Cq + tid];
    __syncthreads();

    const int t  = tid & 31;
    const int nl = tid >> 5;
    const int n  = n0 + nl;

    float x0[Cq], x1[Cq];
    #pragma unroll
    for (int c4 = 0; c4 < 8; c4++) {
        float4 a = *(const float4*)&xs[t*260 + nl*32 + 4*c4];
        x0[4*c4+0]=a.x; x0[4*c4+1]=a.y; x0[4*c4+2]=a.z; x0[4*c4+3]=a.w;
        float4 bb = *(const float4*)&xs[(t+2)*260 + nl*32 + 4*c4];
        x1[4*c4+0]=bb.x; x1[4*c4+1]=bb.y; x1[4*c4+2]=bb.z; x1[4*c4+3]=bb.w;
    }

    float go[Cq];
    float* o1base = out1 + (size_t)b*(Cq*Nq*TPq) + n*TPq + t;

    #pragma unroll
    for (int o = 0; o < Cq; o++) {
        float a1 = bg1[o], a2 = bg2[o];          // uniform -> scalar loads
        #pragma unroll
        for (int c4 = 0; c4 < 8; c4++) {
            // wg1/wg2 layout [o][c][1][2]: idx = o*64 + c*2 + tap
            // p0 = (w1a[4c4], w1b[4c4], w1a[4c4+1], w1b[4c4+1]) etc.
            const float4 p0 = *(const float4*)&wg1[o*64 + 8*c4];
            const float4 p1 = *(const float4*)&wg1[o*64 + 8*c4 + 4];
            const float4 q0 = *(const float4*)&wg2[o*64 + 8*c4];
            const float4 q1 = *(const float4*)&wg2[o*64 + 8*c4 + 4];
            a1 = fmaf(x0[4*c4+0], p0.x, a1); a1 = fmaf(x1[4*c4+0], p0.y, a1);
            a1 = fmaf(x0[4*c4+1], p0.z, a1); a1 = fmaf(x1[4*c4+1], p0.w, a1);
            a1 = fmaf(x0[4*c4+2], p1.x, a1); a1 = fmaf(x1[4*c4+2], p1.y, a1);
            a1 = fmaf(x0[4*c4+3], p1.z, a1); a1 = fmaf(x1[4*c4+3], p1.w, a1);
            a2 = fmaf(x0[4*c4+0], q0.x, a2); a2 = fmaf(x1[4*c4+0], q0.y, a2);
            a2 = fmaf(x0[4*c4+1], q0.z, a2); a2 = fmaf(x1[4*c4+1], q0.w, a2);
            a2 = fmaf(x0[4*c4+2], q1.x, a2); a2 = fmaf(x1[4*c4+2], q1.y, a2);
            a2 = fmaf(x0[4*c4+3], q1.z, a2); a2 = fmaf(x1[4*c4+3], q1.w, a2);
        }
        const float g = fast_tanh(a1) * fast_sigmoid(a2);
        go[o] = g;
        o1base[(size_t)o * (Nq*TPq)] = g;
    }

    // deferred GCN linear: xwa[c] = sum_d go[d] * wgcn[c][d] (rows contiguous)
    float xwa[Cq];
    #pragma unroll
    for (int c = 0; c < Cq; c++) {
        float acc = 0.f;
        #pragma unroll
        for (int d4 = 0; d4 < 8; d4++) {
            const float4 w = *(const float4*)&wgcn[c*Cq + 4*d4];   // uniform
            acc = fmaf(go[4*d4+0], w.x, acc);
            acc = fmaf(go[4*d4+1], w.y, acc);
            acc = fmaf(go[4*d4+2], w.z, acc);
            acc = fmaf(go[4*d4+3], w.w, acc);
        }
        xwa[c] = acc;
    }

    // bf16-pack + swizzled write: g = b*32 + t == (b*Tp + t)
    const int g  = b*32 + t;
    const int s  = g >> 8;
    const int gl = g & 255;
    #pragma unroll
    for (int c8 = 0; c8 < 4; c8++) {
        uint4 u;
        u.x = pack_bf16x2(xwa[8*c8+0], xwa[8*c8+1]);
        u.y = pack_bf16x2(xwa[8*c8+2], xwa[8*c8+3]);
        u.z = pack_bf16x2(xwa[8*c8+4], xwa[8*c8+5]);
        u.w = pack_bf16x2(xwa[8*c8+6], xwa[8*c8+7]);
        xw4[((size_t)(n*2 + s)*4 + c8)*256 + gl] = u;
    }
}

// ---------------------------------------------------------------------------
// Single-block graph prep: LDS degree/count atomics -> LDS scan -> CSR fill.
// ---------------------------------------------------------------------------
__global__ __launch_bounds__(1024) void k_graph(
    const int* __restrict__ ei, const float* __restrict__ ew,
    float* __restrict__ dis_g, int* __restrict__ rowstart_g,
    int* __restrict__ col, float* __restrict__ val)
{
    __shared__ float deg[Nq];
    __shared__ int   cnt[Nq];
    __shared__ int   pos[Nq];
    __shared__ float diss[Nq];
    __shared__ int   ssum[1024];
    const int tid = threadIdx.x;

    for (int n = tid; n < Nq; n += 1024) { deg[n] = 1.0f; cnt[n] = 0; }
    __syncthreads();
    for (int e = tid; e < Eq; e += 1024) {
        int d = ei[Eq + e];
        atomicAdd(&deg[d], ew[e]);
        atomicAdd(&cnt[d], 1);
    }
    __syncthreads();
    const int v = (tid < Nq) ? cnt[tid] : 0;
    ssum[tid] = v;
    __syncthreads();
    for (int off = 1; off < 1024; off <<= 1) {
        int add = (tid >= off) ? ssum[tid - off] : 0;
        __syncthreads();
        ssum[tid] += add;
        __syncthreads();
    }
    if (tid < Nq) {
        int excl = ssum[tid] - v;
        pos[tid] = excl;
        rowstart_g[tid] = excl;
        float di = rsqrtf(deg[tid]);    // deg >= 1 (self loop)
        diss[tid] = di;
        dis_g[tid] = di;
        if (tid == Nq-1) rowstart_g[Nq] = ssum[tid];
    }
    __syncthreads();
    for (int e = tid; e < Eq; e += 1024) {
        int srce = ei[e], d = ei[Eq + e];
        int slot = atomicAdd(&pos[d], 1);
        col[slot] = srce;
        val[slot] = diss[srce] * ew[e] * diss[d];
    }
}

// ---------------------------------------------------------------------------
// K3: SpMM gather + fused 1x1 conv. Grid = 2 slices x 1000 rows (slice-major
// for L2/L3 locality: per-slice working set = 16 MB bf16). Thread = one graph
// (32-c accumulator in regs). Per edge: 4 x 16B coalesced loads (1KB/wave).
// ---------------------------------------------------------------------------
__global__ __launch_bounds__(256) void k_gcn(
    const uint4* __restrict__ xw4, const int* __restrict__ rowstart,
    const int* __restrict__ colv, const float* __restrict__ valv,
    const float* __restrict__ dis, const float* __restrict__ bgcn,
    const float* __restrict__ wout, const float* __restrict__ bout,
    float* __restrict__ y)
{
    __shared__ float woT[Cq*OCq];   // woT[c*64+o] = wout[o*32+c]
    __shared__ int   scol[64];
    __shared__ float sval[64];
    const int tid = threadIdx.x;
    const int s   = blockIdx.x / Nq;
    const int i   = blockIdx.x - s*Nq;

    for (int k = tid; k < Cq*OCq; k += 256) {
        int o = k & 63, c = k >> 6;
        woT[k] = wout[o*Cq + c];    // consecutive LDS writes: conflict-free
    }

    float acc[Cq];
    #pragma unroll
    for (int c = 0; c < Cq; c++) acc[c] = 0.f;

    const int r0 = rowstart[i], r1 = rowstart[i+1];
    const int total = r1 - r0 + 1;       // + self loop
    const float dii = dis[i];

    for (int base = 0; base < total; base += 64) {
        const int cnt = min(64, total - base);
        __syncthreads();
        if (tid < cnt) {
            int k = base + tid;
            if (k == 0) { scol[tid] = i; sval[tid] = dii*dii; }
            else        { scol[tid] = colv[r0 + k - 1]; sval[tid] = valv[r0 + k - 1]; }
        }
        __syncthreads();
        for (int k = 0; k < cnt; k++) {
            const int   sc = scol[k];
            const float sv = sval[k];
            const uint4* rp = xw4 + ((size_t)(sc*2 + s)*4)*256 + tid;
            uint4 v[4];
            #pragma unroll
            for (int c8 = 0; c8 < 4; c8++) v[c8] = rp[c8*256];
            #pragma unroll
            for (int c8 = 0; c8 < 4; c8++) {
                acc[8*c8+0] = fmaf(sv, __uint_as_float(v[c8].x << 16),          acc[8*c8+0]);
                acc[8*c8+1] = fmaf(sv, __uint_as_float(v[c8].x & 0xffff0000u), acc[8*c8+1]);
                acc[8*c8+2] = fmaf(sv, __uint_as_float(v[c8].y << 16),          acc[8*c8+2]);
                acc[8*c8+3] = fmaf(sv, __uint_as_float(v[c8].y & 0xffff0000u), acc[8*c8+3]);
                acc[8*c8+4] = fmaf(sv, __uint_as_float(v[c8].z << 16),          acc[8*c8+4]);
                acc[8*c8+5] = fmaf(sv, __uint_as_float(v[c8].z & 0xffff0000u), acc[8*c8+5]);
                acc[8*c8+6] = fmaf(sv, __uint_as_float(v[c8].w << 16),          acc[8*c8+6]);
                acc[8*c8+7] = fmaf(sv, __uint_as_float(v[c8].w & 0xffff0000u), acc[8*c8+7]);
            }
        }
    }

    #pragma unroll
    for (int c4 = 0; c4 < 8; c4++) {
        const float4 bg = *(const float4*)&bgcn[4*c4];   // uniform
        acc[4*c4+0] += bg.x; acc[4*c4+1] += bg.y;
        acc[4*c4+2] += bg.z; acc[4*c4+3] += bg.w;
    }

    // fused 1x1 out-conv, two 32-output halves (register-bounded)
    const int g = s*256 + tid;
    float* yp = y + ((size_t)g*Nq + i)*OCq;
    #pragma unroll
    for (int h = 0; h < 2; h++) {
        float yr[32];
        #pragma unroll
        for (int q = 0; q < 32; q++) yr[q] = bout[h*32 + q];   // uniform
        #pragma unroll
        for (int c = 0; c < Cq; c++) {
            const float ga = acc[c];
            const float* wrow = &woT[c*OCq + h*32];
            #pragma unroll
            for (int q4 = 0; q4 < 8; q4++) {
                const float4 w = *(const float4*)&wrow[4*q4];  // broadcast
                yr[4*q4+0] = fmaf(ga, w.x, yr[4*q4+0]);
                yr[4*q4+1] = fmaf(ga, w.y, yr[4*q4+1]);
                yr[4*q4+2] = fmaf(ga, w.z, yr[4*q4+2]);
                yr[4*q4+3] = fmaf(ga, w.w, yr[4*q4+3]);
            }
        }
        #pragma unroll
        for (int q4 = 0; q4 < 8; q4++) {
            float4 vv;
            vv.x = yr[4*q4+0]; vv.y = yr[4*q4+1];
            vv.z = yr[4*q4+2]; vv.w = yr[4*q4+3];
            *(float4*)&yp[h*32 + 4*q4] = vv;
        }
    }
}

// ---------------------------------------------------------------------------
extern "C" void kernel_launch(void* const* d_in, const int* in_sizes, int n_in,
                              void* d_out, int out_size, void* d_ws, size_t ws_size,
                              hipStream_t stream)
{
    const float* x    = (const float*)d_in[0];
    const int*   ei   = (const int*)  d_in[1];
    const float* ew   = (const float*)d_in[2];
    const float* wg1  = (const float*)d_in[3];
    const float* bg1  = (const float*)d_in[4];
    const float* wg2  = (const float*)d_in[5];
    const float* bg2  = (const float*)d_in[6];
    const float* wgcn = (const float*)d_in[7];
    const float* bgcn = (const float*)d_in[8];
    const float* wout = (const float*)d_in[9];
    const float* bout = (const float*)d_in[10];

    float* out1 = (float*)d_out;                         // [B,32,N,32]
    float* y    = out1 + (size_t)Bq*Cq*Nq*TPq;           // [B,32,N,64]

    char* ws = (char*)d_ws;
    uint4* xwt = (uint4*)ws; ws += sizeof(unsigned short)*(size_t)Nq*Gq*Cq; // 32.8MB
    float* dis = (float*)ws; ws += sizeof(float)*Nq;
    float* val = (float*)ws; ws += sizeof(float)*Eq;
    int*   col = (int*)ws;   ws += sizeof(int)*Eq;
    int*   rowstart = (int*)ws; ws += sizeof(int)*(Nq+4);

    k_conv<<<Bq*NG8, 256, 0, stream>>>(x, wg1, bg1, wg2, bg2, wgcn, out1, xwt);
    k_graph<<<1, 1024, 0, stream>>>(ei, ew, dis, rowstart, col, val);
    k_gcn<<<2*Nq, 256, 0, stream>>>(xwt, rowstart, col, val, dis,
                                    bgcn, wout, bout, y);
}

// Round 2
// 590.881 us; speedup vs baseline: 1.0695x; 1.0695x over previous
//
#include <hip/hip_runtime.h>
#include <math.h>

#define Bq 16
#define Tq 34
#define Nq 1000
#define Cq 32      // CIN == DC == 32
#define OCq 64
#define Eq 16000
#define TPq 32     // T - dilation
#define Gq (Bq*TPq)  // 512 graphs
#define NG8 (Nq/8)   // 125

__device__ __forceinline__ float fast_tanh(float x) {
    float xc = fminf(fmaxf(x, -15.f), 15.f);
    float u  = __expf(2.f * xc);
    return 1.f - 2.f * __builtin_amdgcn_rcpf(u + 1.f);
}
__device__ __forceinline__ float fast_sigmoid(float x) {
    float xc = fminf(fmaxf(x, -30.f), 30.f);
    return __builtin_amdgcn_rcpf(1.f + __expf(-xc));
}
__device__ __forceinline__ unsigned bf16_bits(float f) {
    unsigned u = __float_as_uint(f);
    return (u + 0x7fffu + ((u >> 16) & 1u)) >> 16;   // RNE
}
__device__ __forceinline__ unsigned pack_bf16x2(float lo, float hi) {
    return bf16_bits(lo) | (bf16_bits(hi) << 16);
}

// ---------------------------------------------------------------------------
// K1: fused dilated gated conv -> out1 [B,32,N,32] (fp32)  and
//     xwt = gated @ Wgcn^T packed bf16, layout uint4[(n*2+s)*4 + c8][gl].
//
// NO LDS AT ALL. Each thread loads its x0/x1 (2 x 128B contiguous) straight
// from global and an asm keep-alive PINS them in VGPRs: the previous two
// versions both ran at 230 us because LLVM rematerialized the x tile from
// LDS inside the o-loop (~512 hidden ds_read_b128/thread -> DS-pipe bound;
// the VGPR count of 68 < the 96 live values proved it). With the x values
// forced into registers the o-loop is pure s_load(weights)+FMA.
// ---------------------------------------------------------------------------
__global__ __launch_bounds__(256) void k_conv(
    const float* __restrict__ x,
    const float* __restrict__ wg1, const float* __restrict__ bg1,
    const float* __restrict__ wg2, const float* __restrict__ bg2,
    const float* __restrict__ wgcn,
    float* __restrict__ out1, uint4* __restrict__ xw4)
{
    const int tid = threadIdx.x;
    const int b   = blockIdx.x / NG8;
    const int n0  = (blockIdx.x % NG8) * 8;

    const int t  = tid & 31;
    const int nl = tid >> 5;
    const int n  = n0 + nl;

    // x layout [B,T,N,C]: per-thread rows are 128B contiguous (full lines)
    const float* xp0 = x + ((size_t)(b*Tq + t    )*Nq + n)*Cq;
    const float* xp1 = x + ((size_t)(b*Tq + t + 2)*Nq + n)*Cq;

    float x0[Cq], x1[Cq];
    #pragma unroll
    for (int c4 = 0; c4 < 8; c4++) {
        float4 a = *(const float4*)&xp0[4*c4];
        x0[4*c4+0]=a.x; x0[4*c4+1]=a.y; x0[4*c4+2]=a.z; x0[4*c4+3]=a.w;
        float4 bb = *(const float4*)&xp1[4*c4];
        x1[4*c4+0]=bb.x; x1[4*c4+1]=bb.y; x1[4*c4+2]=bb.z; x1[4*c4+3]=bb.w;
    }
    // Pin in registers: forbid rematerialization / re-load of the x values.
    #pragma unroll
    for (int c = 0; c < Cq; c++)
        asm volatile("" : "+v"(x0[c]), "+v"(x1[c]));

    float go[Cq];
    float* o1base = out1 + (size_t)b*(Cq*Nq*TPq) + n*TPq + t;

    #pragma unroll
    for (int o = 0; o < Cq; o++) {
        float a1 = bg1[o], a2 = bg2[o];          // uniform -> scalar loads
        #pragma unroll
        for (int c4 = 0; c4 < 8; c4++) {
            // wg1/wg2 layout [o][c][1][2]: idx = o*64 + c*2 + tap
            const float4 p0 = *(const float4*)&wg1[o*64 + 8*c4];
            const float4 p1 = *(const float4*)&wg1[o*64 + 8*c4 + 4];
            const float4 q0 = *(const float4*)&wg2[o*64 + 8*c4];
            const float4 q1 = *(const float4*)&wg2[o*64 + 8*c4 + 4];
            a1 = fmaf(x0[4*c4+0], p0.x, a1); a1 = fmaf(x1[4*c4+0], p0.y, a1);
            a1 = fmaf(x0[4*c4+1], p0.z, a1); a1 = fmaf(x1[4*c4+1], p0.w, a1);
            a1 = fmaf(x0[4*c4+2], p1.x, a1); a1 = fmaf(x1[4*c4+2], p1.y, a1);
            a1 = fmaf(x0[4*c4+3], p1.z, a1); a1 = fmaf(x1[4*c4+3], p1.w, a1);
            a2 = fmaf(x0[4*c4+0], q0.x, a2); a2 = fmaf(x1[4*c4+0], q0.y, a2);
            a2 = fmaf(x0[4*c4+1], q0.z, a2); a2 = fmaf(x1[4*c4+1], q0.w, a2);
            a2 = fmaf(x0[4*c4+2], q1.x, a2); a2 = fmaf(x1[4*c4+2], q1.y, a2);
            a2 = fmaf(x0[4*c4+3], q1.z, a2); a2 = fmaf(x1[4*c4+3], q1.w, a2);
        }
        const float g = fast_tanh(a1) * fast_sigmoid(a2);
        go[o] = g;
        o1base[(size_t)o * (Nq*TPq)] = g;
    }

    // deferred GCN linear: xwa[c] = sum_d go[d] * wgcn[c][d] (rows contiguous)
    float xwa[Cq];
    #pragma unroll
    for (int c = 0; c < Cq; c++) {
        float acc = 0.f;
        #pragma unroll
        for (int d4 = 0; d4 < 8; d4++) {
            const float4 w = *(const float4*)&wgcn[c*Cq + 4*d4];   // uniform
            acc = fmaf(go[4*d4+0], w.x, acc);
            acc = fmaf(go[4*d4+1], w.y, acc);
            acc = fmaf(go[4*d4+2], w.z, acc);
            acc = fmaf(go[4*d4+3], w.w, acc);
        }
        xwa[c] = acc;
    }

    // bf16-pack + swizzled write: g = b*32 + t == (b*Tp + t)
    const int g  = b*32 + t;
    const int s  = g >> 8;
    const int gl = g & 255;
    #pragma unroll
    for (int c8 = 0; c8 < 4; c8++) {
        uint4 u;
        u.x = pack_bf16x2(xwa[8*c8+0], xwa[8*c8+1]);
        u.y = pack_bf16x2(xwa[8*c8+2], xwa[8*c8+3]);
        u.z = pack_bf16x2(xwa[8*c8+4], xwa[8*c8+5]);
        u.w = pack_bf16x2(xwa[8*c8+6], xwa[8*c8+7]);
        xw4[((size_t)(n*2 + s)*4 + c8)*256 + gl] = u;
    }
}

// ---------------------------------------------------------------------------
// Single-block graph prep: LDS degree/count atomics -> LDS scan -> CSR fill.
// ---------------------------------------------------------------------------
__global__ __launch_bounds__(1024) void k_graph(
    const int* __restrict__ ei, const float* __restrict__ ew,
    float* __restrict__ dis_g, int* __restrict__ rowstart_g,
    int* __restrict__ col, float* __restrict__ val)
{
    __shared__ float deg[Nq];
    __shared__ int   cnt[Nq];
    __shared__ int   pos[Nq];
    __shared__ float diss[Nq];
    __shared__ int   ssum[1024];
    const int tid = threadIdx.x;

    for (int n = tid; n < Nq; n += 1024) { deg[n] = 1.0f; cnt[n] = 0; }
    __syncthreads();
    for (int e = tid; e < Eq; e += 1024) {
        int d = ei[Eq + e];
        atomicAdd(&deg[d], ew[e]);
        atomicAdd(&cnt[d], 1);
    }
    __syncthreads();
    const int v = (tid < Nq) ? cnt[tid] : 0;
    ssum[tid] = v;
    __syncthreads();
    for (int off = 1; off < 1024; off <<= 1) {
        int add = (tid >= off) ? ssum[tid - off] : 0;
        __syncthreads();
        ssum[tid] += add;
        __syncthreads();
    }
    if (tid < Nq) {
        int excl = ssum[tid] - v;
        pos[tid] = excl;
        rowstart_g[tid] = excl;
        float di = rsqrtf(deg[tid]);    // deg >= 1 (self loop)
        diss[tid] = di;
        dis_g[tid] = di;
        if (tid == Nq-1) rowstart_g[Nq] = ssum[tid];
    }
    __syncthreads();
    for (int e = tid; e < Eq; e += 1024) {
        int srce = ei[e], d = ei[Eq + e];
        int slot = atomicAdd(&pos[d], 1);
        col[slot] = srce;
        val[slot] = diss[srce] * ew[e] * diss[d];
    }
}

// ---------------------------------------------------------------------------
// K3: SpMM gather + fused 1x1 conv. Grid = 2 slices x 1000 rows (slice-major
// for L2/L3 locality: per-slice working set = 16 MB bf16). Thread = one graph
// (32-c accumulator in regs). Per edge: 4 x 16B coalesced loads (1KB/wave).
// ---------------------------------------------------------------------------
__global__ __launch_bounds__(256) void k_gcn(
    const uint4* __restrict__ xw4, const int* __restrict__ rowstart,
    const int* __restrict__ colv, const float* __restrict__ valv,
    const float* __restrict__ dis, const float* __restrict__ bgcn,
    const float* __restrict__ wout, const float* __restrict__ bout,
    float* __restrict__ y)
{
    __shared__ float woT[Cq*OCq];   // woT[c*64+o] = wout[o*32+c]
    __shared__ int   scol[64];
    __shared__ float sval[64];
    const int tid = threadIdx.x;
    const int s   = blockIdx.x / Nq;
    const int i   = blockIdx.x - s*Nq;

    for (int k = tid; k < Cq*OCq; k += 256) {
        int o = k & 63, c = k >> 6;
        woT[k] = wout[o*Cq + c];    // consecutive LDS writes: conflict-free
    }

    float acc[Cq];
    #pragma unroll
    for (int c = 0; c < Cq; c++) acc[c] = 0.f;

    const int r0 = rowstart[i], r1 = rowstart[i+1];
    const int total = r1 - r0 + 1;       // + self loop
    const float dii = dis[i];

    for (int base = 0; base < total; base += 64) {
        const int cnt = min(64, total - base);
        __syncthreads();
        if (tid < cnt) {
            int k = base + tid;
            if (k == 0) { scol[tid] = i; sval[tid] = dii*dii; }
            else        { scol[tid] = colv[r0 + k - 1]; sval[tid] = valv[r0 + k - 1]; }
        }
        __syncthreads();
        for (int k = 0; k < cnt; k++) {
            const int   sc = scol[k];
            const float sv = sval[k];
            const uint4* rp = xw4 + ((size_t)(sc*2 + s)*4)*256 + tid;
            uint4 v[4];
            #pragma unroll
            for (int c8 = 0; c8 < 4; c8++) v[c8] = rp[c8*256];
            #pragma unroll
            for (int c8 = 0; c8 < 4; c8++) {
                acc[8*c8+0] = fmaf(sv, __uint_as_float(v[c8].x << 16),          acc[8*c8+0]);
                acc[8*c8+1] = fmaf(sv, __uint_as_float(v[c8].x & 0xffff0000u), acc[8*c8+1]);
                acc[8*c8+2] = fmaf(sv, __uint_as_float(v[c8].y << 16),          acc[8*c8+2]);
                acc[8*c8+3] = fmaf(sv, __uint_as_float(v[c8].y & 0xffff0000u), acc[8*c8+3]);
                acc[8*c8+4] = fmaf(sv, __uint_as_float(v[c8].z << 16),          acc[8*c8+4]);
                acc[8*c8+5] = fmaf(sv, __uint_as_float(v[c8].z & 0xffff0000u), acc[8*c8+5]);
                acc[8*c8+6] = fmaf(sv, __uint_as_float(v[c8].w << 16),          acc[8*c8+6]);
                acc[8*c8+7] = fmaf(sv, __uint_as_float(v[c8].w & 0xffff0000u), acc[8*c8+7]);
            }
        }
    }

    #pragma unroll
    for (int c4 = 0; c4 < 8; c4++) {
        const float4 bg = *(const float4*)&bgcn[4*c4];   // uniform
        acc[4*c4+0] += bg.x; acc[4*c4+1] += bg.y;
        acc[4*c4+2] += bg.z; acc[4*c4+3] += bg.w;
    }

    // fused 1x1 out-conv, two 32-output halves (register-bounded)
    const int g = s*256 + tid;
    float* yp = y + ((size_t)g*Nq + i)*OCq;
    #pragma unroll
    for (int h = 0; h < 2; h++) {
        float yr[32];
        #pragma unroll
        for (int q = 0; q < 32; q++) yr[q] = bout[h*32 + q];   // uniform
        #pragma unroll
        for (int c = 0; c < Cq; c++) {
            const float ga = acc[c];
            const float* wrow = &woT[c*OCq + h*32];
            #pragma unroll
            for (int q4 = 0; q4 < 8; q4++) {
                const float4 w = *(const float4*)&wrow[4*q4];  // broadcast
                yr[4*q4+0] = fmaf(ga, w.x, yr[4*q4+0]);
                yr[4*q4+1] = fmaf(ga, w.y, yr[4*q4+1]);
                yr[4*q4+2] = fmaf(ga, w.z, yr[4*q4+2]);
                yr[4*q4+3] = fmaf(ga, w.w, yr[4*q4+3]);
            }
        }
        #pragma unroll
        for (int q4 = 0; q4 < 8; q4++) {
            float4 vv;
            vv.x = yr[4*q4+0]; vv.y = yr[4*q4+1];
            vv.z = yr[4*q4+2]; vv.w = yr[4*q4+3];
            *(float4*)&yp[h*32 + 4*q4] = vv;
        }
    }
}

// ---------------------------------------------------------------------------
extern "C" void kernel_launch(void* const* d_in, const int* in_sizes, int n_in,
                              void* d_out, int out_size, void* d_ws, size_t ws_size,
                              hipStream_t stream)
{
    const float* x    = (const float*)d_in[0];
    const int*   ei   = (const int*)  d_in[1];
    const float* ew   = (const float*)d_in[2];
    const float* wg1  = (const float*)d_in[3];
    const float* bg1  = (const float*)d_in[4];
    const float* wg2  = (const float*)d_in[5];
    const float* bg2  = (const float*)d_in[6];
    const float* wgcn = (const float*)d_in[7];
    const float* bgcn = (const float*)d_in[8];
    const float* wout = (const float*)d_in[9];
    const float* bout = (const float*)d_in[10];

    float* out1 = (float*)d_out;                         // [B,32,N,32]
    float* y    = out1 + (size_t)Bq*Cq*Nq*TPq;           // [B,32,N,64]

    char* ws = (char*)d_ws;
    uint4* xwt = (uint4*)ws; ws += sizeof(unsigned short)*(size_t)Nq*Gq*Cq; // 32.8MB
    float* dis = (float*)ws; ws += sizeof(float)*Nq;
    float* val = (float*)ws; ws += sizeof(float)*Eq;
    int*   col = (int*)ws;   ws += sizeof(int)*Eq;
    int*   rowstart = (int*)ws; ws += sizeof(int)*(Nq+4);

    k_conv<<<Bq*NG8, 256, 0, stream>>>(x, wg1, bg1, wg2, bg2, wgcn, out1, xwt);
    k_graph<<<1, 1024, 0, stream>>>(ei, ew, dis, rowstart, col, val);
    k_gcn<<<2*Nq, 256, 0, stream>>>(xwt, rowstart, col, val, dis,
                                    bgcn, wout, bout, y);
}

// Round 3
// 490.250 us; speedup vs baseline: 1.2890x; 1.2053x over previous
//
#include <hip/hip_runtime.h>
#include <math.h>

#define Bq 16
#define Tq 34
#define Nq 1000
#define Cq 32      // CIN == DC == 32
#define OCq 64
#define Eq 16000
#define TPq 32     // T - dilation
#define Gq (Bq*TPq)  // 512 graphs

typedef _Float16 f16;
typedef f16  f16x8 __attribute__((ext_vector_type(8)));
typedef float f32x4 __attribute__((ext_vector_type(4)));

__device__ __forceinline__ float fast_tanh(float x) {
    float xc = fminf(fmaxf(x, -15.f), 15.f);
    float u  = __expf(2.f * xc);
    return 1.f - 2.f * __builtin_amdgcn_rcpf(u + 1.f);
}
__device__ __forceinline__ float fast_sigmoid(float x) {
    float xc = fminf(fmaxf(x, -30.f), 30.f);
    return __builtin_amdgcn_rcpf(1.f + __expf(-xc));
}
__device__ __forceinline__ unsigned bf16_bits(float f) {
    unsigned u = __float_as_uint(f);
    return (u + 0x7fffu + ((u >> 16) & 1u)) >> 16;   // RNE
}
__device__ __forceinline__ unsigned pack_bf16x2(float lo, float hi) {
    return bf16_bits(lo) | (bf16_bits(hi) << 16);
}

// ---------------------------------------------------------------------------
// K0: precompute f16 MFMA A-fragments for the conv weights and wgcn.
// Stage-1 A[row=o][k], k = ks*32 + c (ks = tap). Frag layout per
// mfma_f32_16x16x32_f16: lane l holds A[l&15][(l>>4)*8 + j], j=0..7.
// fid = gate*4 + otile*2 + ks  (8 frags, 1 KB each) ; then 2 frags for wgcn
// (A2[row=c][k=o]).
// ---------------------------------------------------------------------------
__global__ __launch_bounds__(640) void k_prep(
    const float* __restrict__ wg1, const float* __restrict__ wg2,
    const float* __restrict__ wgcn, f16* __restrict__ fragbuf)
{
    const int tid = threadIdx.x;
    if (tid < 512) {
        const int fid  = tid >> 6;            // 0..7
        const int lane = tid & 63;
        const int gate  = fid >> 2;
        const int otile = (fid >> 1) & 1;
        const int ks    = fid & 1;            // = tap
        const float* w = gate ? wg2 : wg1;    // layout [o][c][1][2]
        const int o = otile*16 + (lane & 15);
        f16* dst = fragbuf + (size_t)fid*512 + lane*8;
        #pragma unroll
        for (int j = 0; j < 8; j++) {
            const int c = (lane >> 4)*8 + j;
            dst[j] = (f16)w[o*64 + c*2 + ks];
        }
    } else if (tid < 640) {
        const int l2 = tid - 512;
        const int ctile = l2 >> 6;
        const int lane  = l2 & 63;
        const int c = ctile*16 + (lane & 15);
        f16* dst = fragbuf + (size_t)8*512 + ((size_t)ctile*64 + lane)*8;
        #pragma unroll
        for (int j = 0; j < 8; j++) {
            const int o = (lane >> 4)*8 + j;
            dst[j] = (f16)wgcn[c*32 + o];     // wgcn[c][d=o]
        }
    }
}

// ---------------------------------------------------------------------------
// K1: MFMA gated conv + GCN linear.
// Block = one (b,n), 128 threads = 2 waves; wave w owns o-tile w (16 o's).
// Stage 1: C1[o][t] (gate1) and C2[o][t] (gate2) via 8 MFMA / wave
//   (A=weights precomputed frags, B=x loaded f32->f16; C layout row=o,col=t
//    means gate1/gate2 pair in SAME lane+reg -> elementwise gating).
// go -> out1 (4x64B-seg stores) and f16 into LDS [t][o] (stride 40).
// Stage 2: xw[c][t] = wgcn x go  (2 MFMA / wave, K=32 over o), bf16-pack,
//   store uint2 at [(n*2+s)*8 + c/4][gl].
// ---------------------------------------------------------------------------
__global__ __launch_bounds__(128) void k_conv(
    const float* __restrict__ x,
    const float* __restrict__ bg1, const float* __restrict__ bg2,
    const f16* __restrict__ fragbuf,
    float* __restrict__ out1, uint2* __restrict__ xw2)
{
    __shared__ f16 goS[32*40];            // [t][o], stride 40 h (80B rows)
    const int tid  = threadIdx.x;
    const int w    = tid >> 6;            // wave = o-tile
    const int lane = tid & 63;
    const int b    = blockIdx.x / Nq;
    const int n    = blockIdx.x % Nq;
    const int tq   = lane & 15;
    const int cg   = lane >> 4;

    const uint4* fb = (const uint4*)fragbuf;      // 16B per lane-entry
    union cvu { uint4 u; f16x8 h; };
    cvu A1k0; A1k0.u = fb[(0 + w*2 + 0)*64 + lane];
    cvu A1k1; A1k1.u = fb[(0 + w*2 + 1)*64 + lane];
    cvu A2k0; A2k0.u = fb[(4 + w*2 + 0)*64 + lane];
    cvu A2k1; A2k1.u = fb[(4 + w*2 + 1)*64 + lane];

    // B-frags: lane -> B[k=(cg*8+j) + ks*32][t=tt*16+tq] = x[b][t+2ks][n][c]
    f16x8 Bf[2][2];
    #pragma unroll
    for (int tt = 0; tt < 2; tt++) {
        #pragma unroll
        for (int ks = 0; ks < 2; ks++) {
            const float* xp = x + (((size_t)(b*Tq + tt*16 + tq + ks*2))*Nq + n)*Cq + cg*8;
            const float4 lo = *(const float4*)xp;
            const float4 hi = *(const float4*)(xp + 4);
            f16x8 h;
            h[0]=(f16)lo.x; h[1]=(f16)lo.y; h[2]=(f16)lo.z; h[3]=(f16)lo.w;
            h[4]=(f16)hi.x; h[5]=(f16)hi.y; h[6]=(f16)hi.z; h[7]=(f16)hi.w;
            Bf[tt][ks] = h;
        }
    }

    f32x4 acc1[2] = {{0.f,0.f,0.f,0.f},{0.f,0.f,0.f,0.f}};
    f32x4 acc2[2] = {{0.f,0.f,0.f,0.f},{0.f,0.f,0.f,0.f}};
    #pragma unroll
    for (int tt = 0; tt < 2; tt++) {
        acc1[tt] = __builtin_amdgcn_mfma_f32_16x16x32_f16(A1k0.h, Bf[tt][0], acc1[tt], 0,0,0);
        acc1[tt] = __builtin_amdgcn_mfma_f32_16x16x32_f16(A1k1.h, Bf[tt][1], acc1[tt], 0,0,0);
        acc2[tt] = __builtin_amdgcn_mfma_f32_16x16x32_f16(A2k0.h, Bf[tt][0], acc2[tt], 0,0,0);
        acc2[tt] = __builtin_amdgcn_mfma_f32_16x16x32_f16(A2k1.h, Bf[tt][1], acc2[tt], 0,0,0);
    }

    const int obase = w*16 + cg*4;
    const float4 b1 = *(const float4*)&bg1[obase];
    const float4 b2 = *(const float4*)&bg2[obase];
    const float b1a[4] = {b1.x,b1.y,b1.z,b1.w};
    const float b2a[4] = {b2.x,b2.y,b2.z,b2.w};

    float* o1base = out1 + ((size_t)b*Cq + obase)*(Nq*TPq) + (size_t)n*TPq;
    #pragma unroll
    for (int tt = 0; tt < 2; tt++) {
        const int t = tt*16 + tq;
        f16* gp = &goS[t*40 + obase];
        #pragma unroll
        for (int r = 0; r < 4; r++) {
            const float a1 = acc1[tt][r] + b1a[r];
            const float a2 = acc2[tt][r] + b2a[r];
            const float go = fast_tanh(a1) * fast_sigmoid(a2);
            o1base[(size_t)r*(Nq*TPq) + t] = go;
            gp[r] = (f16)go;
        }
    }
    __syncthreads();

    // Stage 2: xw[c][t], K=32 over o. B2 lane: go[o=cg*8+j][t], 16B-aligned.
    cvu A2f; A2f.u = fb[8*64 + w*64 + lane];       // c-tile = w
    #pragma unroll
    for (int tt = 0; tt < 2; tt++) {
        const int t = tt*16 + tq;
        const f16x8 B2 = *(const f16x8*)&goS[t*40 + cg*8];
        f32x4 xa = {0.f,0.f,0.f,0.f};
        xa = __builtin_amdgcn_mfma_f32_16x16x32_f16(A2f.h, B2, xa, 0,0,0);
        const int g  = b*32 + t;
        const int s  = g >> 8;
        const int gl = g & 255;
        const int cbase = w*16 + cg*4;             // row = c
        uint2 u;
        u.x = pack_bf16x2(xa[0], xa[1]);
        u.y = pack_bf16x2(xa[2], xa[3]);
        xw2[((size_t)(n*2 + s)*8 + (cbase >> 2))*256 + gl] = u;
    }
}

// ---------------------------------------------------------------------------
// Single-block graph prep: LDS degree/count atomics -> LDS scan -> CSR fill.
// ---------------------------------------------------------------------------
__global__ __launch_bounds__(1024) void k_graph(
    const int* __restrict__ ei, const float* __restrict__ ew,
    float* __restrict__ dis_g, int* __restrict__ rowstart_g,
    int* __restrict__ col, float* __restrict__ val)
{
    __shared__ float deg[Nq];
    __shared__ int   cnt[Nq];
    __shared__ int   pos[Nq];
    __shared__ float diss[Nq];
    __shared__ int   ssum[1024];
    const int tid = threadIdx.x;

    for (int n = tid; n < Nq; n += 1024) { deg[n] = 1.0f; cnt[n] = 0; }
    __syncthreads();
    for (int e = tid; e < Eq; e += 1024) {
        int d = ei[Eq + e];
        atomicAdd(&deg[d], ew[e]);
        atomicAdd(&cnt[d], 1);
    }
    __syncthreads();
    const int v = (tid < Nq) ? cnt[tid] : 0;
    ssum[tid] = v;
    __syncthreads();
    for (int off = 1; off < 1024; off <<= 1) {
        int add = (tid >= off) ? ssum[tid - off] : 0;
        __syncthreads();
        ssum[tid] += add;
        __syncthreads();
    }
    if (tid < Nq) {
        int excl = ssum[tid] - v;
        pos[tid] = excl;
        rowstart_g[tid] = excl;
        float di = rsqrtf(deg[tid]);    // deg >= 1 (self loop)
        diss[tid] = di;
        dis_g[tid] = di;
        if (tid == Nq-1) rowstart_g[Nq] = ssum[tid];
    }
    __syncthreads();
    for (int e = tid; e < Eq; e += 1024) {
        int srce = ei[e], d = ei[Eq + e];
        int slot = atomicAdd(&pos[d], 1);
        col[slot] = srce;
        val[slot] = diss[srce] * ew[e] * diss[d];
    }
}

// ---------------------------------------------------------------------------
// K3: SpMM gather + fused 1x1 conv. Grid = 2 slices x 1000 rows. Thread = one
// graph. Per edge: 8 x 8B coalesced loads (same bytes as before, uint2 layout
// to match the MFMA producer: element [(n*2+s)*8 + c/4][gl]).
// ---------------------------------------------------------------------------
__global__ __launch_bounds__(256) void k_gcn(
    const uint2* __restrict__ xw2, const int* __restrict__ rowstart,
    const int* __restrict__ colv, const float* __restrict__ valv,
    const float* __restrict__ dis, const float* __restrict__ bgcn,
    const float* __restrict__ wout, const float* __restrict__ bout,
    float* __restrict__ y)
{
    __shared__ float woT[Cq*OCq];   // woT[c*64+o] = wout[o*32+c]
    __shared__ int   scol[64];
    __shared__ float sval[64];
    const int tid = threadIdx.x;
    const int s   = blockIdx.x / Nq;
    const int i   = blockIdx.x - s*Nq;

    for (int k = tid; k < Cq*OCq; k += 256) {
        int o = k & 63, c = k >> 6;
        woT[k] = wout[o*Cq + c];
    }

    float acc[Cq];
    #pragma unroll
    for (int c = 0; c < Cq; c++) acc[c] = 0.f;

    const int r0 = rowstart[i], r1 = rowstart[i+1];
    const int total = r1 - r0 + 1;       // + self loop
    const float dii = dis[i];

    for (int base = 0; base < total; base += 64) {
        const int cnt = min(64, total - base);
        __syncthreads();
        if (tid < cnt) {
            int k = base + tid;
            if (k == 0) { scol[tid] = i; sval[tid] = dii*dii; }
            else        { scol[tid] = colv[r0 + k - 1]; sval[tid] = valv[r0 + k - 1]; }
        }
        __syncthreads();
        for (int k = 0; k < cnt; k++) {
            const int   sc = scol[k];
            const float sv = sval[k];
            const uint2* rp = xw2 + ((size_t)(sc*2 + s)*8)*256 + tid;
            uint2 v[8];
            #pragma unroll
            for (int cg = 0; cg < 8; cg++) v[cg] = rp[cg*256];
            #pragma unroll
            for (int cg = 0; cg < 8; cg++) {
                acc[4*cg+0] = fmaf(sv, __uint_as_float(v[cg].x << 16),          acc[4*cg+0]);
                acc[4*cg+1] = fmaf(sv, __uint_as_float(v[cg].x & 0xffff0000u), acc[4*cg+1]);
                acc[4*cg+2] = fmaf(sv, __uint_as_float(v[cg].y << 16),          acc[4*cg+2]);
                acc[4*cg+3] = fmaf(sv, __uint_as_float(v[cg].y & 0xffff0000u), acc[4*cg+3]);
            }
        }
    }

    #pragma unroll
    for (int c4 = 0; c4 < 8; c4++) {
        const float4 bg = *(const float4*)&bgcn[4*c4];   // uniform
        acc[4*c4+0] += bg.x; acc[4*c4+1] += bg.y;
        acc[4*c4+2] += bg.z; acc[4*c4+3] += bg.w;
    }

    const int g = s*256 + tid;
    float* yp = y + ((size_t)g*Nq + i)*OCq;
    #pragma unroll
    for (int h = 0; h < 2; h++) {
        float yr[32];
        #pragma unroll
        for (int q = 0; q < 32; q++) yr[q] = bout[h*32 + q];   // uniform
        #pragma unroll
        for (int c = 0; c < Cq; c++) {
            const float ga = acc[c];
            const float* wrow = &woT[c*OCq + h*32];
            #pragma unroll
            for (int q4 = 0; q4 < 8; q4++) {
                const float4 w = *(const float4*)&wrow[4*q4];  // broadcast
                yr[4*q4+0] = fmaf(ga, w.x, yr[4*q4+0]);
                yr[4*q4+1] = fmaf(ga, w.y, yr[4*q4+1]);
                yr[4*q4+2] = fmaf(ga, w.z, yr[4*q4+2]);
                yr[4*q4+3] = fmaf(ga, w.w, yr[4*q4+3]);
            }
        }
        #pragma unroll
        for (int q4 = 0; q4 < 8; q4++) {
            float4 vv;
            vv.x = yr[4*q4+0]; vv.y = yr[4*q4+1];
            vv.z = yr[4*q4+2]; vv.w = yr[4*q4+3];
            *(float4*)&yp[h*32 + 4*q4] = vv;
        }
    }
}

// ---------------------------------------------------------------------------
extern "C" void kernel_launch(void* const* d_in, const int* in_sizes, int n_in,
                              void* d_out, int out_size, void* d_ws, size_t ws_size,
                              hipStream_t stream)
{
    const float* x    = (const float*)d_in[0];
    const int*   ei   = (const int*)  d_in[1];
    const float* ew   = (const float*)d_in[2];
    const float* wg1  = (const float*)d_in[3];
    const float* bg1  = (const float*)d_in[4];
    const float* wg2  = (const float*)d_in[5];
    const float* bg2  = (const float*)d_in[6];
    const float* wgcn = (const float*)d_in[7];
    const float* bgcn = (const float*)d_in[8];
    const float* wout = (const float*)d_in[9];
    const float* bout = (const float*)d_in[10];

    float* out1 = (float*)d_out;                         // [B,32,N,32]
    float* y    = out1 + (size_t)Bq*Cq*Nq*TPq;           // [B,32,N,64]

    char* ws = (char*)d_ws;
    uint2* xwt = (uint2*)ws; ws += sizeof(unsigned short)*(size_t)Nq*Gq*Cq; // 32.8MB
    float* dis = (float*)ws; ws += sizeof(float)*Nq;
    float* val = (float*)ws; ws += sizeof(float)*Eq;
    int*   col = (int*)ws;   ws += sizeof(int)*Eq;
    int*   rowstart = (int*)ws; ws += sizeof(int)*(Nq+4);
    f16*   fragbuf  = (f16*)ws; ws += sizeof(f16)*(10*512);

    k_prep<<<1, 640, 0, stream>>>(wg1, wg2, wgcn, fragbuf);
    k_conv<<<Bq*Nq, 128, 0, stream>>>(x, bg1, bg2, fragbuf, out1, xwt);
    k_graph<<<1, 1024, 0, stream>>>(ei, ew, dis, rowstart, col, val);
    k_gcn<<<2*Nq, 256, 0, stream>>>(xwt, rowstart, col, val, dis,
                                    bgcn, wout, bout, y);
}